// Round 2
// baseline (439.521 us; speedup 1.0000x reference)
//
#include <hip/hip_runtime.h>

#define N_NODES 8192
#define N_EDGES 65536
#define FEAT    136
#define WNUM    3392

typedef __attribute__((ext_vector_type(4))) short s16x4;
typedef __attribute__((ext_vector_type(8))) short s16x8;
typedef __attribute__((ext_vector_type(4))) float f32x4;

__device__ __forceinline__ float b2f(unsigned short h) {
    union { unsigned int u; float f; } v; v.u = ((unsigned int)h) << 16; return v.f;
}
__device__ __forceinline__ unsigned short f2b(float f) {
    union { float f; unsigned int u; } v; v.f = f;
    unsigned int u = v.u;
    unsigned int r = (u + 0x7FFFu + ((u >> 16) & 1u)) >> 16;
    return (unsigned short)r;
}

// ---- prep: W2 (64x3392 f32) -> w2t (3392x64 bf16); W1 (64x64 f32) -> w1t (64x64 bf16 T) ----
__global__ void transpose_kernel(const float* __restrict__ w2,
                                 const float* __restrict__ w1,
                                 unsigned short* __restrict__ w2t,
                                 unsigned short* __restrict__ w1t) {
    __shared__ unsigned short tl[64 * 65];
    const int b = blockIdx.x, tid = threadIdx.x;
    if (b < 53) {
        const int c0 = b * 64;
        for (int idx = tid; idx < 4096; idx += 256) {
            int k = idx >> 6, c = idx & 63;
            tl[c * 65 + k] = f2b(w2[k * WNUM + c0 + c]);   // coalesced read over c
        }
        __syncthreads();
        for (int idx = tid; idx < 4096; idx += 256) {
            int c = idx >> 6, k = idx & 63;
            w2t[(c0 + c) * 64 + k] = tl[c * 65 + k];       // coalesced write over k
        }
    } else {
        for (int idx = tid; idx < 4096; idx += 256) {
            int k = idx >> 6, j = idx & 63;
            tl[j * 65 + k] = f2b(w1[k * 64 + j]);
        }
        __syncthreads();
        for (int idx = tid; idx < 4096; idx += 256) {
            int j = idx >> 6, k = idx & 63;
            w1t[j * 64 + k] = tl[j * 65 + k];
        }
    }
}

// ---------------- fused main kernel: 64 edges per block ----------------
__global__ __launch_bounds__(256, 2)
void tpconv_main(const float* __restrict__ node_attr,
                 const int* __restrict__ edge_index,
                 const float* __restrict__ edge_attr,
                 const float* __restrict__ edge_sh,
                 const unsigned short* __restrict__ w1t,
                 const float* __restrict__ b1,
                 const unsigned short* __restrict__ w2t,
                 const float* __restrict__ b2,
                 float* __restrict__ acc_g,
                 float* __restrict__ cnt_g) {
    // strides: 72 shorts = 144 B (16B multiple -> aligned b128, 2-way banks = free)
    __shared__ unsigned short h_lds[64 * 72];     // h tile bf16, [edge][k]
    __shared__ unsigned short o_lds[64 * 388];    // o factors bf16 (scaled), [edge][384]
    __shared__ unsigned short xw_lds[9216];       // union: x gather bf16 (64*144) / W2 dbuf (2*64*72)
    __shared__ float sh_lds[64 * 4];
    __shared__ int src_lds[64];
    __shared__ int dst_lds[64];

    const int tid  = threadIdx.x;
    const int lane = tid & 63;
    const int wv   = tid >> 6;       // wave 0..3 -> 16-edge stripe
    const int n    = lane & 15;
    const int quad = lane >> 4;
    const int eb   = blockIdx.x * 64;

    // ---- step 1: indices, sh, counts ----
    if (tid < 64) {
        int s = edge_index[eb + tid];
        int d = edge_index[N_EDGES + eb + tid];
        src_lds[tid] = s;
        dst_lds[tid] = d;
        atomicAdd(&cnt_g[s], 1.0f);
        const float4 shv = *(const float4*)&edge_sh[(size_t)(eb + tid) * 4];
        sh_lds[tid * 4 + 0] = shv.x;
        sh_lds[tid * 4 + 1] = shv.y;
        sh_lds[tid * 4 + 2] = shv.z;
        sh_lds[tid * 4 + 3] = shv.w;
    }

    // ---- h phase: h = relu(ea @ W1 + b1) via MFMA, write h_lds ----
    {
        const float* ea = edge_attr + (size_t)(eb + wv * 16 + n) * 64 + quad * 8;
        s16x8 a0, a1;
#pragma unroll
        for (int j = 0; j < 8; ++j) {
            a0[j] = (short)f2b(ea[j]);        // A[m=n][k=quad*8+j]
            a1[j] = (short)f2b(ea[32 + j]);
        }
        for (int ct = 0; ct < 4; ++ct) {
            int col = ct * 16 + n;
            const unsigned short* wp = w1t + col * 64;  // B[k][n] = W1T[col][k]
            s16x8 bu0 = *(const s16x8*)&wp[quad * 8];
            s16x8 bu1 = *(const s16x8*)&wp[32 + quad * 8];
            f32x4 acc = {0.f, 0.f, 0.f, 0.f};
            acc = __builtin_amdgcn_mfma_f32_16x16x32_bf16(a0, bu0, acc, 0, 0, 0);
            acc = __builtin_amdgcn_mfma_f32_16x16x32_bf16(a1, bu1, acc, 0, 0, 0);
            float bias = b1[col];
            for (int r = 0; r < 4; ++r) {
                float hv = acc[r] + bias;
                hv = hv > 0.f ? hv : 0.f;
                // D: col=lane&15, row(edge)=quad*4+r
                h_lds[(wv * 16 + quad * 4 + r) * 72 + col] = f2b(hv);
            }
        }
    }
    __syncthreads();   // dst_lds visible

    // ---- x gather: node_attr[dst] rows (f32) -> bf16 into xw_lds ----
    for (int idx = tid; idx < 64 * 34; idx += 256) {
        int e = idx / 34, seg = idx - e * 34;             // 34 float4 segs = 136 floats
        const float4 v = *(const float4*)(node_attr + (size_t)dst_lds[e] * FEAT + seg * 4);
        s16x4 pk;
        pk[0] = (short)f2b(v.x); pk[1] = (short)f2b(v.y);
        pk[2] = (short)f2b(v.z); pk[3] = (short)f2b(v.w);
        *(s16x4*)&xw_lds[e * 144 + seg * 4] = pk;
    }
    __syncthreads();   // x, sh visible

    // ---- build o factors (block 1/sqrt(in) scales folded in) ----
    {
        const int e = tid >> 2;
        const int q = tid & 3;
        const float sh0 = sh_lds[e * 4 + 0];
        const float s1x = sh_lds[e * 4 + 1], s1y = sh_lds[e * 4 + 2], s1z = sh_lds[e * 4 + 3];
        const unsigned short* xr = &xw_lds[e * 144];
        const float inv_s3 = 0.57735026918962576f;
        const float inv_s2 = 0.70710678118654752f;
        const float sc0e = 0.14433756729740643f;   // 1/sqrt(48)
        const float sc1o = 0.125f;                 // 1/sqrt(64)
        const float sc1e = 0.15811388300841897f;   // 1/sqrt(40)
        const float sc0o = 0.20412414523193150f;   // 1/sqrt(24)
        for (int p = q * 96; p < q * 96 + 96; ++p) {
            float val;
            if (p < 48) {                                    // o0e: 48
                if (p < 32) val = b2f(xr[p]) * sh0 * sc0e;
                else {
                    int i = p - 32;
                    val = (b2f(xr[32 + i * 3]) * s1x + b2f(xr[33 + i * 3]) * s1y +
                           b2f(xr[34 + i * 3]) * s1z) * (inv_s3 * sc0e);
                }
            } else if (p < 240) {                            // o1o: (i=0..63, c) at 48+i*3+c
                int r = p - 48;
                int i = r / 3, c = r - i * 3;
                float s1c = sh_lds[e * 4 + 1 + c];
                if (i < 32) val = b2f(xr[i]) * s1c * sc1o;
                else if (i < 48) val = b2f(xr[32 + (i - 32) * 3 + c]) * sh0 * sc1o;
                else {
                    int ii = i - 48;
                    int c1 = (c == 2) ? 0 : c + 1, c2 = (c == 0) ? 2 : c - 1;
                    val = (b2f(xr[80 + ii * 3 + c1]) * sh_lds[e * 4 + 1 + c2] -
                           b2f(xr[80 + ii * 3 + c2]) * sh_lds[e * 4 + 1 + c1]) * (inv_s2 * sc1o);
                }
            } else if (p < 360) {                            // o1e: (i=0..39, c) at 240+i*3+c
                int r = p - 240;
                int i = r / 3, c = r - i * 3;
                float s1c = sh_lds[e * 4 + 1 + c];
                if (i < 16) {
                    int c1 = (c == 2) ? 0 : c + 1, c2 = (c == 0) ? 2 : c - 1;
                    val = (b2f(xr[32 + i * 3 + c1]) * sh_lds[e * 4 + 1 + c2] -
                           b2f(xr[32 + i * 3 + c2]) * sh_lds[e * 4 + 1 + c1]) * (inv_s2 * sc1e);
                } else if (i < 32) {
                    val = b2f(xr[80 + (i - 16) * 3 + c]) * sh0 * sc1e;
                } else {
                    val = b2f(xr[128 + (i - 32)]) * s1c * sc1e;
                }
            } else {                                         // o0o: 24 at 360+i
                int i = p - 360;
                if (i < 16) val = (b2f(xr[80 + i * 3]) * s1x + b2f(xr[81 + i * 3]) * s1y +
                                   b2f(xr[82 + i * 3]) * s1z) * (inv_s3 * sc0o);
                else val = b2f(xr[128 + (i - 16)]) * sh0 * sc0o;
            }
            o_lds[e * 388 + p] = f2b(val);
        }
    }
    __syncthreads();   // o_lds + h_lds ready; xw_lds now free for W2 staging

    // ---- persistent A fragments (this wave's 16 edges) ----
    const unsigned short* hp = &h_lds[(wv * 16 + n) * 72];
    s16x8 a0 = *(const s16x8*)&hp[quad * 8];
    s16x8 a1 = *(const s16x8*)&hp[32 + quad * 8];

    float Y0e[4][2] = {};
    float Y1o[4][3] = {};
    float Y1e[4][3] = {};
    float Y0o[4]    = {};

    int eoff[4];
    for (int r = 0; r < 4; ++r) eoff[r] = (wv * 16 + quad * 4 + r) * 388;

    unsigned short* wbuf0 = xw_lds;
    unsigned short* wbuf1 = xw_lds + 64 * 72;
    const int scol = tid >> 2, sseg = tid & 3;

    // prefetch chunk 0 of W2T into registers
    s16x8 g0, g1;
    {
        const unsigned short* gp = w2t + (size_t)scol * 64 + sseg * 16;
        g0 = *(const s16x8*)gp;
        g1 = *(const s16x8*)(gp + 8);
    }

    for (int c = 0; c < 53; ++c) {
        unsigned short* buf = (c & 1) ? wbuf1 : wbuf0;
        *(s16x8*)&buf[scol * 72 + sseg * 16]     = g0;
        *(s16x8*)&buf[scol * 72 + sseg * 16 + 8] = g1;
        __syncthreads();
        if (c < 52) {
            const unsigned short* gp = w2t + (size_t)(c + 1) * 4096 + (size_t)scol * 64 + sseg * 16;
            g0 = *(const s16x8*)gp;
            g1 = *(const s16x8*)(gp + 8);
        }
        const int c0 = c * 64;
        int blk, ibase;
        if (c0 < 1536)      { blk = 0; ibase = c0 >> 5; }
        else if (c0 < 2560) { blk = 1; ibase = (c0 - 1536) >> 4; }
        else if (c0 < 3200) { blk = 2; ibase = (c0 - 2560) >> 4; }
        else                { blk = 3; ibase = (c0 - 3200) >> 3; }

        float o_c[4];
        for (int t = 0; t < 4; ++t) {
            const int cl = t * 16 + n;
            const unsigned short* bp = &buf[cl * 72];
            s16x8 b0v = *(const s16x8*)&bp[quad * 8];
            s16x8 b1v = *(const s16x8*)&bp[32 + quad * 8];
            f32x4 acc = {0.f, 0.f, 0.f, 0.f};
            acc = __builtin_amdgcn_mfma_f32_16x16x32_bf16(a0, b0v, acc, 0, 0, 0);
            acc = __builtin_amdgcn_mfma_f32_16x16x32_bf16(a1, b1v, acc, 0, 0, 0);
            const float bias = b2[c0 + cl];
            // lane holds w for col=c0+cl, edges wv*16+quad*4+r  -> contract in registers
            if (blk == 0) {                       // out-stride 32: col = i*32 + kk*16 + n
                int i = ibase + (t >> 1);
                if ((t & 1) == 0)
                    for (int r = 0; r < 4; ++r) o_c[r] = b2f(o_lds[eoff[r] + i]);
                int kk = t & 1;
                for (int r = 0; r < 4; ++r)
                    Y0e[r][kk] += o_c[r] * (acc[r] + bias);
            } else if (blk == 1) {                // col = 1536 + i*16 + n  (n = output o)
                int i = ibase + t;
                for (int r = 0; r < 4; ++r) {
                    float wvv = acc[r] + bias;
                    int ob = eoff[r] + 48 + i * 3;
                    Y1o[r][0] += b2f(o_lds[ob + 0]) * wvv;
                    Y1o[r][1] += b2f(o_lds[ob + 1]) * wvv;
                    Y1o[r][2] += b2f(o_lds[ob + 2]) * wvv;
                }
            } else if (blk == 2) {                // col = 2560 + i*16 + n
                int i = ibase + t;
                for (int r = 0; r < 4; ++r) {
                    float wvv = acc[r] + bias;
                    int ob = eoff[r] + 240 + i * 3;
                    Y1e[r][0] += b2f(o_lds[ob + 0]) * wvv;
                    Y1e[r][1] += b2f(o_lds[ob + 1]) * wvv;
                    Y1e[r][2] += b2f(o_lds[ob + 2]) * wvv;
                }
            } else {                              // out-stride 8: col = 3200 + i*8 + (n&7)
                int i = ibase + 2 * t + (n >> 3);
                for (int r = 0; r < 4; ++r)
                    Y0o[r] += b2f(o_lds[eoff[r] + 360 + i]) * (acc[r] + bias);
            }
        }
    }

    // ---- scatter: atomic add into node accumulators (by src) ----
    for (int r = 0; r < 4; ++r) {
        int el = wv * 16 + quad * 4 + r;
        float* dp = acc_g + (size_t)src_lds[el] * FEAT;
        atomicAdd(dp + n,                Y0e[r][0]);
        atomicAdd(dp + 16 + n,           Y0e[r][1]);
        atomicAdd(dp + 32 + n * 3 + 0,   Y1o[r][0]);
        atomicAdd(dp + 32 + n * 3 + 1,   Y1o[r][1]);
        atomicAdd(dp + 32 + n * 3 + 2,   Y1o[r][2]);
        atomicAdd(dp + 80 + n * 3 + 0,   Y1e[r][0]);
        atomicAdd(dp + 80 + n * 3 + 1,   Y1e[r][1]);
        atomicAdd(dp + 80 + n * 3 + 2,   Y1e[r][2]);
        atomicAdd(dp + 128 + (n & 7),    Y0o[r]);
    }
}

// ---------------- finalize: mean + residual (fp32 out) ----------------
__global__ void finalize_kernel(const float* __restrict__ acc_g,
                                const float* __restrict__ cnt_g,
                                const float* __restrict__ node_attr,
                                float* __restrict__ out) {
    int idx = blockIdx.x * 256 + threadIdx.x;
    if (idx >= N_NODES * FEAT) return;
    int nn = idx / FEAT;
    float c = cnt_g[nn];
    out[idx] = acc_g[idx] / fmaxf(c, 1.0f) + node_attr[idx];
}

extern "C" void kernel_launch(void* const* d_in, const int* in_sizes, int n_in,
                              void* d_out, int out_size, void* d_ws, size_t ws_size,
                              hipStream_t stream) {
    const float* node_attr  = (const float*)d_in[0];
    const int*   edge_index = (const int*)d_in[1];
    const float* edge_attr  = (const float*)d_in[2];
    const float* edge_sh    = (const float*)d_in[3];
    const float* fc_w1      = (const float*)d_in[4];
    const float* fc_b1      = (const float*)d_in[5];
    const float* fc_w2      = (const float*)d_in[6];
    const float* fc_b2      = (const float*)d_in[7];
    float* out = (float*)d_out;

    char* ws = (char*)d_ws;
    float* acc_g = (float*)ws;                                      // 8192*136*4 = 4456448
    float* cnt_g = (float*)(ws + 4456448);                          // 8192*4     = 32768
    unsigned short* w2t = (unsigned short*)(ws + 4489216);          // 3392*64*2  = 434176
    unsigned short* w1t = (unsigned short*)(ws + 4489216 + 434176); // 64*64*2    = 8192

    hipMemsetAsync(ws, 0, 4489216, stream);  // zero acc + cnt (ws is re-poisoned every call)
    transpose_kernel<<<54, 256, 0, stream>>>(fc_w2, fc_w1, w2t, w1t);
    tpconv_main<<<1024, 256, 0, stream>>>(node_attr, edge_index, edge_attr, edge_sh,
                                          w1t, fc_b1, w2t, fc_b2, acc_g, cnt_g);
    finalize_kernel<<<(N_NODES * FEAT + 255) / 256, 256, 0, stream>>>(acc_g, cnt_g, node_attr, out);
}